// Round 1
// baseline (107.921 us; speedup 1.0000x reference)
//
#include <hip/hip_runtime.h>

// PerturbedTopK: per (b,n) row of d=1024, top-k (k=102) indices of
// x[b] + sigma*noise[b,n], sorted ascending; out[b, rank, idx] += 1/n.
// One 256-thread block per row; radix-select threshold + prefix-scan ranks.

#define D_DIM 1024
#define K_SEL 102
#define BLOCK 256
#define SIGMA 0.05f

__device__ __forceinline__ unsigned int float_to_key(float f) {
    unsigned int u = __float_as_uint(f);
    // order-preserving map: larger float -> larger uint
    return (u & 0x80000000u) ? ~u : (u | 0x80000000u);
}

__global__ __launch_bounds__(BLOCK)
void ptopk_kernel(const float* __restrict__ x,
                  const float* __restrict__ noise,
                  float* __restrict__ out,
                  int n_samples, float inv_n) {
    const int row = blockIdx.x;            // row in [0, b*n)
    const int bb  = row / n_samples;
    const int tid = threadIdx.x;

    // ---- load 4 elements/thread, build orderable keys ----
    const float4 nv = reinterpret_cast<const float4*>(noise + (size_t)row * D_DIM)[tid];
    const float4 xv = reinterpret_cast<const float4*>(x     + (size_t)bb  * D_DIM)[tid];

    unsigned int key[4];
    key[0] = float_to_key(fmaf(nv.x, SIGMA, xv.x));
    key[1] = float_to_key(fmaf(nv.y, SIGMA, xv.y));
    key[2] = float_to_key(fmaf(nv.z, SIGMA, xv.z));
    key[3] = float_to_key(fmaf(nv.w, SIGMA, xv.w));

    __shared__ unsigned int hist[BLOCK];
    __shared__ unsigned int scan[BLOCK];
    __shared__ unsigned int s_sel[2];   // [0]=digit, [1]=count of strictly-greater buckets

    // ---- radix select: find k-th largest key (exact 32-bit threshold) ----
    unsigned int prefix = 0u, pmask = 0u;
    unsigned int kk = K_SEL;

    for (int shift = 24; shift >= 0; shift -= 8) {
        hist[tid] = 0u;
        __syncthreads();
        #pragma unroll
        for (int j = 0; j < 4; ++j) {
            if ((key[j] & pmask) == prefix)
                atomicAdd(&hist[(key[j] >> shift) & 0xFFu], 1u);
        }
        __syncthreads();

        // inclusive suffix scan: scan[t] = sum_{u>=t} hist[u]
        scan[tid] = hist[tid];
        __syncthreads();
        #pragma unroll
        for (int off = 1; off < BLOCK; off <<= 1) {
            unsigned int add = (tid + off < BLOCK) ? scan[tid + off] : 0u;
            __syncthreads();
            scan[tid] += add;
            __syncthreads();
        }

        unsigned int ge = scan[tid];                          // count(digit >= tid)
        unsigned int gt = (tid < BLOCK - 1) ? scan[tid + 1] : 0u; // count(digit > tid)
        if (gt < kk && kk <= ge) {                            // unique crossing bucket
            s_sel[0] = (unsigned int)tid;
            s_sel[1] = gt;
        }
        __syncthreads();
        prefix |= (s_sel[0] << shift);
        pmask  |= (0xFFu << shift);
        kk     -= s_sel[1];
        __syncthreads();
    }

    const unsigned int T   = prefix;  // exact k-th largest key
    const unsigned int kkf = kk;      // # of elements == T that are selected (>=1)

    // ---- rank computation: rank(i) = #selected indices < i ----
    bool isGT[4], isEQ[4];
    unsigned int local = 0u;          // packed: (GT count << 16) | EQ count
    #pragma unroll
    for (int j = 0; j < 4; ++j) {
        isGT[j] = key[j] > T;
        isEQ[j] = key[j] == T;
        local += (isGT[j] ? 0x10000u : 0u) + (isEQ[j] ? 1u : 0u);
    }

    scan[tid] = local;
    __syncthreads();
    #pragma unroll
    for (int off = 1; off < BLOCK; off <<= 1) {
        unsigned int add = (tid >= off) ? scan[tid - off] : 0u;
        __syncthreads();
        scan[tid] += add;
        __syncthreads();
    }
    unsigned int run = scan[tid] - local;   // exclusive prefix (packed)

    float* orow = out + (size_t)bb * K_SEL * D_DIM;
    #pragma unroll
    for (int j = 0; j < 4; ++j) {
        const unsigned int gtp = run >> 16;
        const unsigned int eqp = run & 0xFFFFu;
        const int i = tid * 4 + j;
        if (isGT[j]) {
            const unsigned int rank = gtp + (eqp < kkf ? eqp : kkf);
            atomicAdd(orow + (size_t)rank * D_DIM + i, inv_n);
            run += 0x10000u;
        } else if (isEQ[j]) {
            if (eqp < kkf)
                atomicAdd(orow + (size_t)(gtp + eqp) * D_DIM + i, inv_n);
            run += 1u;
        }
    }
}

extern "C" void kernel_launch(void* const* d_in, const int* in_sizes, int n_in,
                              void* d_out, int out_size, void* d_ws, size_t ws_size,
                              hipStream_t stream) {
    const float* x     = (const float*)d_in[0];
    const float* noise = (const float*)d_in[1];
    float* out = (float*)d_out;

    const int d = D_DIM;                       // 1024
    const int b = in_sizes[0] / d;             // 32
    const int n = in_sizes[1] / in_sizes[0];   // 250
    const int rows = b * n;                    // 8000

    // harness poisons d_out with 0xAA and never re-poisons between replays:
    // zero it every call before the atomic scatter.
    hipMemsetAsync(d_out, 0, (size_t)out_size * sizeof(float), stream);

    ptopk_kernel<<<rows, BLOCK, 0, stream>>>(x, noise, out, n, 1.0f / (float)n);
}

// Round 2
// 95.885 us; speedup vs baseline: 1.1255x; 1.1255x over previous
//
#include <hip/hip_runtime.h>

// PerturbedTopK: per (b,n) row of d=1024, top-k (k=102) indices of
// x[b] + sigma*noise[b,n], sorted ascending; out[b, rank, idx] += 1/n.
//
// One WAVE (64 lanes) per row, 16 elements/lane. Selection by bitwise
// binary search with __ballot counting (no LDS, no __syncthreads).
// Dead keys are zeroed in place (key==0 is the negative-NaN bit pattern,
// unreachable from finite inputs). Ranks via one shfl_up prefix scan.

#define D_DIM 1024
#define K_SEL 102
#define SIGMA 0.05f
#define WAVES_PER_BLOCK 4
#define BLOCK (WAVES_PER_BLOCK * 64)
#define SLOTS 16  // D_DIM / 64 elements per lane

__device__ __forceinline__ unsigned int float_to_key(float f) {
    unsigned int u = __float_as_uint(f);
    // order-preserving map: larger float -> larger uint
    return (u & 0x80000000u) ? ~u : (u | 0x80000000u);
}

__global__ __launch_bounds__(BLOCK)
void ptopk_kernel(const float* __restrict__ x,
                  const float* __restrict__ noise,
                  float* __restrict__ out,
                  int n_samples, float inv_n, int rows) {
    const int wid  = threadIdx.x >> 6;
    const int lane = threadIdx.x & 63;
    const int row  = blockIdx.x * WAVES_PER_BLOCK + wid;
    if (row >= rows) return;                    // wave-uniform
    const int bb = row / n_samples;

    // lane owns contiguous elements [lane*16, lane*16+16)
    const float4* nrow =
        reinterpret_cast<const float4*>(noise + (size_t)row * D_DIM + lane * SLOTS);
    const float4* xrow =
        reinterpret_cast<const float4*>(x + (size_t)bb * D_DIM + lane * SLOTS);

    unsigned int key[SLOTS];
    #pragma unroll
    for (int c = 0; c < 4; ++c) {
        const float4 nv = nrow[c];
        const float4 xv = xrow[c];
        key[c * 4 + 0] = float_to_key(fmaf(nv.x, SIGMA, xv.x));
        key[c * 4 + 1] = float_to_key(fmaf(nv.y, SIGMA, xv.y));
        key[c * 4 + 2] = float_to_key(fmaf(nv.z, SIGMA, xv.z));
        key[c * 4 + 3] = float_to_key(fmaf(nv.w, SIGMA, xv.w));
    }

    // ---- bitwise top-k select: find selected set without materializing T ----
    unsigned int sel = 0u;          // slot mask: strictly-greater-than-threshold
    unsigned int kk = K_SEL;        // remaining picks (wave-uniform scalar)
    unsigned int c_active = D_DIM;  // live key count

    for (int shift = 31; shift >= 0; --shift) {
        const unsigned int m = 1u << shift;
        unsigned int c1 = 0;
        #pragma unroll
        for (int j = 0; j < SLOTS; ++j)
            c1 += (unsigned int)__popcll(__ballot(key[j] & m));

        if (kk <= c1) {
            // threshold bit = 1: live keys lacking the bit are too small -> dead
            #pragma unroll
            for (int j = 0; j < SLOTS; ++j)
                key[j] = (key[j] & m) ? key[j] : 0u;
            c_active = c1;
        } else {
            // threshold bit = 0: live keys with the bit are definitely selected
            kk -= c1;
            c_active -= c1;
            #pragma unroll
            for (int j = 0; j < SLOTS; ++j) {
                if (key[j] & m) { sel |= (1u << j); key[j] = 0u; }
            }
        }
        if (kk == c_active) break;  // all remaining live keys are selected ties
    }

    unsigned int alive = 0u;        // keys exactly equal to the threshold
    #pragma unroll
    for (int j = 0; j < SLOTS; ++j)
        if (key[j]) alive |= (1u << j);
    const unsigned int kkf = kk;    // # ties to take, ascending index order

    // ---- ranks: exclusive prefix over lanes of packed (gt<<16 | eq) ----
    const unsigned int mine =
        ((unsigned int)__popc(sel) << 16) | (unsigned int)__popc(alive);
    unsigned int incl = mine;
    #pragma unroll
    for (int off = 1; off < 64; off <<= 1) {
        const unsigned int t = __shfl_up(incl, off, 64);
        if (lane >= off) incl += t;
    }
    unsigned int run = incl - mine;  // exclusive prefix (packed)

    float* orow = out + (size_t)bb * (K_SEL * D_DIM);
    const int base_i = lane * SLOTS;
    #pragma unroll
    for (int j = 0; j < SLOTS; ++j) {
        const unsigned int gtp = run >> 16;
        const unsigned int eqp = run & 0xFFFFu;
        if (sel & (1u << j)) {
            const unsigned int rank = gtp + (eqp < kkf ? eqp : kkf);
            atomicAdd(orow + (size_t)rank * D_DIM + (base_i + j), inv_n);
            run += 0x10000u;
        } else if (alive & (1u << j)) {
            if (eqp < kkf)
                atomicAdd(orow + (size_t)(gtp + eqp) * D_DIM + (base_i + j), inv_n);
            run += 1u;
        }
    }
}

extern "C" void kernel_launch(void* const* d_in, const int* in_sizes, int n_in,
                              void* d_out, int out_size, void* d_ws, size_t ws_size,
                              hipStream_t stream) {
    const float* x     = (const float*)d_in[0];
    const float* noise = (const float*)d_in[1];
    float* out = (float*)d_out;

    const int d = D_DIM;                       // 1024
    const int b = in_sizes[0] / d;             // 32
    const int n = in_sizes[1] / in_sizes[0];   // 250
    const int rows = b * n;                    // 8000

    // harness poisons d_out once and never re-poisons between replays:
    // zero it every call before the atomic scatter.
    hipMemsetAsync(d_out, 0, (size_t)out_size * sizeof(float), stream);

    const int grid = (rows + WAVES_PER_BLOCK - 1) / WAVES_PER_BLOCK;
    ptopk_kernel<<<grid, BLOCK, 0, stream>>>(x, noise, out, n, 1.0f / (float)n, rows);
}